// Round 8
// baseline (537.782 us; speedup 1.0000x reference)
//
#include <hip/hip_runtime.h>
#include <hip/hip_bf16.h>
#include <cstdint>
#include <cstddef>

#define T_TOK 4096
#define HID   1024
#define FFN   3584
#define FFI   (2 * FFN)     // interleaved g/u columns: 7168
#define NEXP  8
#define RTOT  (T_TOK * 2)   // total (token, slot) rows = T * top_k
#define MAXT  72            // max 128-row M-tiles: floor(8192/128)+7=71, +1 slack
#define BM 128
#define BN 128
#define BK 64               // K-tile (halves barrier count vs 32)
#define NT1 (FFI / BN)      // 56 N-tiles for gemm1 (interleaved)
#define NT2 (HID / BN)      // 8 N-tiles for gemm2
#define SPLITK2 4           // gemm2 split-K factor (3584 -> 4 x 896)
#define KCH2 (FFN / SPLITK2)

typedef __attribute__((ext_vector_type(8))) short bvec8;   // 8 x bf16 (4 VGPR) MFMA operand
typedef __attribute__((ext_vector_type(4))) short bvec4;
typedef __attribute__((ext_vector_type(4))) float fvec4;   // MFMA accumulator
typedef unsigned short u16;

__device__ __forceinline__ u16 f2b(float f) {
  __bf16 b = (__bf16)f;                 // RNE convert
  return __builtin_bit_cast(u16, b);
}

// async global->LDS, 16B per lane. LDS dest must be wave-uniform base (HW adds lane*16).
__device__ __forceinline__ void gload16(const u16* g, u16* l) {
  __builtin_amdgcn_global_load_lds((const __attribute__((address_space(1))) void*)g,
                                   (__attribute__((address_space(3))) void*)l, 16, 0, 0);
}

// bijective XCD swizzle (m204): contiguous chunk of work per XCD
__device__ __forceinline__ int xcd_swz(int bid, int nwg) {
  int q = nwg >> 3, r = nwg & 7;
  int xcd = bid & 7, sub = bid >> 3;
  return (xcd < r ? xcd * (q + 1) : r * (q + 1) + (xcd - r) * q) + sub;
}

// ---------------- router: logits (fp32), top-2, combine weights, counts, + x->bf16 ------
__global__ void router_kernel(const float* __restrict__ x, const float* __restrict__ gw,
                              float* __restrict__ logits, int* __restrict__ tk_id,
                              float* __restrict__ tk_w, int* __restrict__ counts,
                              u16* __restrict__ xb, int full) {
  const int lane = threadIdx.x & 63;
  const int wid  = threadIdx.x >> 6;
  const int t = blockIdx.x * 4 + wid;          // one token per wave
  const float4* xr = (const float4*)(x + (size_t)t * HID);
  float acc[NEXP] = {0.f, 0.f, 0.f, 0.f, 0.f, 0.f, 0.f, 0.f};
#pragma unroll
  for (int it = 0; it < 4; ++it) {
    int k4 = it * 64 + lane;                   // float4 index, covers H/4 = 256
    float4 xv = xr[k4];
    if (xb) {                                  // fused bf16 cast of x
      bvec4 o;
      o[0] = (short)f2b(xv.x); o[1] = (short)f2b(xv.y);
      o[2] = (short)f2b(xv.z); o[3] = (short)f2b(xv.w);
      *(bvec4*)(xb + (size_t)t * HID + k4 * 4) = o;
    }
    const float* gp = gw + (size_t)k4 * 4 * NEXP;
    float xs[4] = {xv.x, xv.y, xv.z, xv.w};
#pragma unroll
    for (int kk = 0; kk < 4; ++kk) {
      float4 ga = ((const float4*)(gp + kk * NEXP))[0];
      float4 gb = ((const float4*)(gp + kk * NEXP))[1];
      acc[0] += xs[kk] * ga.x; acc[1] += xs[kk] * ga.y;
      acc[2] += xs[kk] * ga.z; acc[3] += xs[kk] * ga.w;
      acc[4] += xs[kk] * gb.x; acc[5] += xs[kk] * gb.y;
      acc[6] += xs[kk] * gb.z; acc[7] += xs[kk] * gb.w;
    }
  }
#pragma unroll
  for (int off = 32; off > 0; off >>= 1) {
#pragma unroll
    for (int e = 0; e < NEXP; ++e) acc[e] += __shfl_xor(acc[e], off, 64);
  }
  if (lane < NEXP) logits[(size_t)t * NEXP + lane] = acc[lane];
  if (full && lane == 0) {
    int e0 = 0; float l0 = acc[0];
#pragma unroll
    for (int e = 1; e < NEXP; ++e) if (acc[e] > l0) { l0 = acc[e]; e0 = e; }
    int e1 = -1; float l1 = -3.4e38f;
#pragma unroll
    for (int e = 0; e < NEXP; ++e) if (e != e0 && acc[e] > l1) { l1 = acc[e]; e1 = e; }
    float w0 = 1.f / (1.f + expf(l1 - l0));
    float w1 = 1.f - w0;
    tk_id[t * 2 + 0] = e0; tk_id[t * 2 + 1] = e1;
    tk_w[t * 2 + 0] = w0;  tk_w[t * 2 + 1] = w1;
    atomicAdd(&counts[e0], 1); atomicAdd(&counts[e1], 1);
  }
}

// ---------------- scan: offsets, tile map (single thread; 8 experts, trivial) -----------
__global__ void scan_kernel(const int* __restrict__ counts, int* __restrict__ offsets,
                            int* __restrict__ cursors, int4* __restrict__ tilemap) {
  if (threadIdx.x != 0) return;
  int off = 0, nt = 0;
  for (int e = 0; e < NEXP; ++e) {
    offsets[e] = off; cursors[e] = 0;
    int c = counts[e];
    for (int tm = 0; tm * BM < c; ++tm)
      tilemap[nt++] = make_int4(e, off + tm * BM, min(BM, c - tm * BM), 0);
    off += c;
  }
  offsets[NEXP] = off;
  for (; nt < MAXT; ++nt) tilemap[nt] = make_int4(-1, 0, 0, 0);
}

// ---------------- scatter: build per-expert sorted row lists ----------------------------
__global__ void scatter_kernel(const int* __restrict__ tk_id, const float* __restrict__ tk_w,
                               const int* __restrict__ offsets, int* __restrict__ cursors,
                               int* __restrict__ rowmap, float* __restrict__ roww) {
  int i = blockIdx.x * 256 + threadIdx.x;      // 0 .. RTOT-1
  int t = i >> 1;
  int e = tk_id[i]; float w = tk_w[i];
  int p = atomicAdd(&cursors[e], 1);
  rowmap[offsets[e] + p] = t; roww[offsets[e] + p] = w;
}

// ---------------- transpose-cast w1/w3 -> interleaved Bi[E][FFI][HID] (LDS-staged) ------
__global__ void transpose_cast_dual_kernel(const float* __restrict__ w1,
                                           const float* __restrict__ w3,
                                           u16* __restrict__ bi) {
  __shared__ __attribute__((aligned(16))) u16 tile[64][72];
  const int z = blockIdx.z, e = z >> 1, half = z & 1;
  const float* src = (half ? w3 : w1) + (size_t)e * HID * FFN;   // [HID][FFN]
  u16* dst = bi + (size_t)e * FFI * HID;
  const int c0 = blockIdx.x * 64, r0 = blockIdx.y * 64;
  const int t = threadIdx.x;
  const int rr = t >> 4, cc = (t & 15) * 4;
#pragma unroll
  for (int it = 0; it < 4; ++it) {
    int r = it * 16 + rr;
    float4 v = *(const float4*)(src + (size_t)(r0 + r) * FFN + c0 + cc);
    tile[cc + 0][r] = f2b(v.x);
    tile[cc + 1][r] = f2b(v.y);
    tile[cc + 2][r] = f2b(v.z);
    tile[cc + 3][r] = f2b(v.w);
  }
  __syncthreads();
  const int cl = t >> 2;            // local col 0..63
  const int och = (t & 3) * 16;
  const int orow = (c0 << 1) + ((cl >> 4) << 5) + (cl & 15) + (half << 4);
  u16* dp = dst + (size_t)orow * HID + r0 + och;
  *(bvec8*)(dp + 0) = *(const bvec8*)&tile[cl][och + 0];
  *(bvec8*)(dp + 8) = *(const bvec8*)&tile[cl][och + 8];
}

// ---------------- transpose-cast w2 [E][FFN][HID] -> w2t [E][HID][FFN] (LDS-staged) -----
__global__ void transpose_cast_w2_kernel(const float* __restrict__ w2, u16* __restrict__ w2t) {
  __shared__ __attribute__((aligned(16))) u16 tile[64][72];
  const int e = blockIdx.z;
  const float* src = w2 + (size_t)e * FFN * HID;   // [FFN][HID]
  u16* dst = w2t + (size_t)e * HID * FFN;          // [HID][FFN]
  const int c0 = blockIdx.x * 64, r0 = blockIdx.y * 64;
  const int t = threadIdx.x;
  const int rr = t >> 4, cc = (t & 15) * 4;
#pragma unroll
  for (int it = 0; it < 4; ++it) {
    int r = it * 16 + rr;
    float4 v = *(const float4*)(src + (size_t)(r0 + r) * HID + c0 + cc);
    tile[cc + 0][r] = f2b(v.x);
    tile[cc + 1][r] = f2b(v.y);
    tile[cc + 2][r] = f2b(v.z);
    tile[cc + 3][r] = f2b(v.w);
  }
  __syncthreads();
  const int cl = t >> 2;
  const int och = (t & 3) * 16;
  u16* dp = dst + (size_t)(c0 + cl) * FFN + r0 + och;
  *(bvec8*)(dp + 0) = *(const bvec8*)&tile[cl][och + 0];
  *(bvec8*)(dp + 8) = *(const bvec8*)&tile[cl][och + 8];
}

// ---------------- GEMM1: 128x128, BK=64, proven R6 2-barrier structure ------------------
__launch_bounds__(256, 3)
__global__ void gemm1_kernel(const u16* __restrict__ xb, const u16* __restrict__ bi,
                             const int* __restrict__ rowmap,
                             const int4* __restrict__ tilemap, u16* __restrict__ hbuf) {
  const int wg = xcd_swz(blockIdx.x, NT1 * MAXT);
  const int mt = wg % MAXT;          // M fastest within an XCD chunk -> B-panel L2 reuse
  const int nt = wg / MAXT;
  int4 ti = tilemap[mt];
  if (ti.x < 0) return;
  const int e = ti.x, rowbase = ti.y, mvalid = ti.z;
  const int n0 = nt * BN;

  __shared__ __attribute__((aligned(128))) u16 As[BM * BK];   // 16KB
  __shared__ __attribute__((aligned(128))) u16 Bs[BN * BK];   // 16KB

  const int tid = threadIdx.x;
  const int lane = tid & 63;
  const int wv = tid >> 6;

  const int srow = tid >> 3;                         // 0..31
  const int csrc = ((tid & 7) ^ (srow & 7)) * 8;     // pre-swizzled source chunk (elems)
  const u16* wb = bi + (size_t)e * FFI * HID;
  const u16* gA[4]; const u16* gB[4];
  u16* lA[4]; u16* lB[4];
#pragma unroll
  for (int r = 0; r < 4; ++r) {
    int row = r * 32 + srow;
    int tok = rowmap[min(rowbase + row, RTOT - 1)];
    gA[r] = xb + (size_t)tok * HID + csrc;
    gB[r] = wb + (size_t)(n0 + row) * HID + csrc;
    lA[r] = &As[(r * 32 + wv * 8) * BK];             // wave-uniform dests
    lB[r] = &Bs[(r * 32 + wv * 8) * BK];
  }

  const int wm = (tid >> 7) & 1, wn = (tid >> 6) & 1;   // 2x2 waves, 64x64 each
  const int l15 = lane & 15;
  const int kg = lane >> 4;                          // 0..3
  const int swz = l15 & 7;
  const int aBase = (wm * 64 + l15) * BK;
  const int bBase = (wn * 64 + l15) * BK;
  const int ch0 = ((0 + kg) ^ swz) * 8;              // ks=0 phys chunk (elems)
  const int ch1 = ((4 + kg) ^ swz) * 8;              // ks=1

  fvec4 acc[4][4] = {};

  for (int kt = 0; kt < HID / BK; ++kt) {            // 16 iters
#pragma unroll
    for (int r = 0; r < 4; ++r) { gload16(gA[r], lA[r]); gA[r] += BK; }
#pragma unroll
    for (int r = 0; r < 4; ++r) { gload16(gB[r], lB[r]); gB[r] += BK; }
    __syncthreads();
    bvec8 a0[4], a1[4];
#pragma unroll
    for (int mi = 0; mi < 4; ++mi) {
      a0[mi] = *(const bvec8*)&As[aBase + mi * 16 * BK + ch0];
      a1[mi] = *(const bvec8*)&As[aBase + mi * 16 * BK + ch1];
    }
#pragma unroll
    for (int ni = 0; ni < 4; ++ni) {
      bvec8 b0 = *(const bvec8*)&Bs[bBase + ni * 16 * BK + ch0];
#pragma unroll
      for (int mi = 0; mi < 4; ++mi)
        acc[mi][ni] = __builtin_amdgcn_mfma_f32_16x16x32_bf16(a0[mi], b0, acc[mi][ni], 0, 0, 0);
      bvec8 b1 = *(const bvec8*)&Bs[bBase + ni * 16 * BK + ch1];
#pragma unroll
      for (int mi = 0; mi < 4; ++mi)
        acc[mi][ni] = __builtin_amdgcn_mfma_f32_16x16x32_bf16(a1[mi], b1, acc[mi][ni], 0, 0, 0);
    }
    __syncthreads();
  }
  // epilogue: pair ni (even=g, odd=u): h = silu(g) * u, bf16
  const int rg4 = (lane >> 4) * 4;
#pragma unroll
  for (int mi = 0; mi < 4; ++mi) {
#pragma unroll
    for (int j = 0; j < 4; ++j) {
      int ml = wm * 64 + mi * 16 + rg4 + j;
      if (ml < mvalid) {
        size_t rowoff = (size_t)(rowbase + ml) * FFN + ((n0 + wn * 64) >> 1);
#pragma unroll
        for (int np = 0; np < 2; ++np) {
          float g = acc[mi][2 * np][j], u = acc[mi][2 * np + 1][j];
          float hv = (g / (1.f + expf(-g))) * u;
          hbuf[rowoff + np * 16 + l15] = f2b(hv);
        }
      }
    }
  }
}

// ---------------- GEMM2: 128x128, BK=64, R6 structure + split-K x4 for load balance -----
// 280 real tiles -> 1120 real blocks (~4.4/CU): kills the 280-on-256-CU tail imbalance.
// Split-K partials combine via the existing fp32 atomicAdd epilogue (commutative).
__launch_bounds__(256, 3)
__global__ void gemm2_kernel(const u16* __restrict__ hbuf, const u16* __restrict__ w2t,
                             const int* __restrict__ rowmap, const float* __restrict__ roww,
                             const int4* __restrict__ tilemap, float* __restrict__ out) {
  const int wg = xcd_swz(blockIdx.x, NT2 * MAXT * SPLITK2);
  const int mt = wg % MAXT;          // M fastest -> B-panel stays in XCD L2
  const int rest = wg / MAXT;
  const int nt = rest % NT2;
  const int sk = rest / NT2;         // 0..3: K chunk [sk*KCH2, (sk+1)*KCH2)
  int4 ti = tilemap[mt];
  if (ti.x < 0) return;
  const int e = ti.x, rowbase = ti.y, mvalid = ti.z;
  const int n0 = nt * BN;
  const int k0 = sk * KCH2;

  __shared__ __attribute__((aligned(128))) u16 As[BM * BK];   // 16KB
  __shared__ __attribute__((aligned(128))) u16 Bs[BN * BK];   // 16KB

  const int tid = threadIdx.x;
  const int lane = tid & 63;
  const int wv = tid >> 6;

  const int srow = tid >> 3;                         // 0..31
  const int csrc = ((tid & 7) ^ (srow & 7)) * 8;
  const u16* wb2 = w2t + (size_t)e * HID * FFN;
  const u16* gA[4]; const u16* gB[4];
  u16* lA[4]; u16* lB[4];
#pragma unroll
  for (int r = 0; r < 4; ++r) {
    int row = r * 32 + srow;
    gA[r] = hbuf + (size_t)min(rowbase + row, RTOT - 1) * FFN + k0 + csrc;
    gB[r] = wb2 + (size_t)(n0 + row) * FFN + k0 + csrc;
    lA[r] = &As[(r * 32 + wv * 8) * BK];
    lB[r] = &Bs[(r * 32 + wv * 8) * BK];
  }

  const int wm = (tid >> 7) & 1, wn = (tid >> 6) & 1;
  const int l15 = lane & 15;
  const int kg = lane >> 4;
  const int swz = l15 & 7;
  const int aBase = (wm * 64 + l15) * BK;
  const int bBase = (wn * 64 + l15) * BK;
  const int ch0 = ((0 + kg) ^ swz) * 8;
  const int ch1 = ((4 + kg) ^ swz) * 8;

  fvec4 acc[4][4] = {};

  for (int kt = 0; kt < KCH2 / BK; ++kt) {           // 14 iters
#pragma unroll
    for (int r = 0; r < 4; ++r) { gload16(gA[r], lA[r]); gA[r] += BK; }
#pragma unroll
    for (int r = 0; r < 4; ++r) { gload16(gB[r], lB[r]); gB[r] += BK; }
    __syncthreads();
    bvec8 a0[4], a1[4];
#pragma unroll
    for (int mi = 0; mi < 4; ++mi) {
      a0[mi] = *(const bvec8*)&As[aBase + mi * 16 * BK + ch0];
      a1[mi] = *(const bvec8*)&As[aBase + mi * 16 * BK + ch1];
    }
#pragma unroll
    for (int ni = 0; ni < 4; ++ni) {
      bvec8 b0 = *(const bvec8*)&Bs[bBase + ni * 16 * BK + ch0];
#pragma unroll
      for (int mi = 0; mi < 4; ++mi)
        acc[mi][ni] = __builtin_amdgcn_mfma_f32_16x16x32_bf16(a0[mi], b0, acc[mi][ni], 0, 0, 0);
      bvec8 b1 = *(const bvec8*)&Bs[bBase + ni * 16 * BK + ch1];
#pragma unroll
      for (int mi = 0; mi < 4; ++mi)
        acc[mi][ni] = __builtin_amdgcn_mfma_f32_16x16x32_bf16(a1[mi], b1, acc[mi][ni], 0, 0, 0);
    }
    __syncthreads();
  }
  // epilogue: weighted atomic combine into out[token]
  const int rg4 = (lane >> 4) * 4;
#pragma unroll
  for (int mi = 0; mi < 4; ++mi) {
#pragma unroll
    for (int j = 0; j < 4; ++j) {
      int ml = wm * 64 + mi * 16 + rg4 + j;
      if (ml < mvalid) {
        int r = rowbase + ml;
        int tk = rowmap[r];
        float wgt = roww[r];
        float* op = out + (size_t)tk * HID + n0 + wn * 64;
#pragma unroll
        for (int ni = 0; ni < 4; ++ni)
          atomicAdd(&op[ni * 16 + l15], acc[mi][ni][j] * wgt);
      }
    }
  }
}

// ---------------- launcher --------------------------------------------------------------
extern "C" void kernel_launch(void* const* d_in, const int* in_sizes, int n_in,
                              void* d_out, int out_size, void* d_ws, size_t ws_size,
                              hipStream_t stream) {
  (void)in_sizes; (void)n_in; (void)out_size;
  const float* x  = (const float*)d_in[0];
  const float* gw = (const float*)d_in[1];
  const float* w1 = (const float*)d_in[2];
  const float* w2 = (const float*)d_in[3];   // NOTE: dict order is w1, w2, w3
  const float* w3 = (const float*)d_in[4];
  float* out = (float*)d_out;
  float* logits = out + (size_t)T_TOK * HID;

  size_t off = 0;
  auto take = [&](size_t b) { size_t o = off; off += (b + 255) & ~(size_t)255; return o; };
  size_t o_xb   = take((size_t)T_TOK * HID * 2);           // x bf16
  size_t o_wt   = take((size_t)NEXP * FFI * HID * 2);      // Bi (interleaved w1/w3); w2t reuses
  size_t o_hb   = take((size_t)RTOT * FFN * 2);            // h bf16
  size_t o_rmap = take((size_t)RTOT * 4);
  size_t o_rw   = take((size_t)RTOT * 4);
  size_t o_tid  = take((size_t)RTOT * 4);
  size_t o_tw   = take((size_t)RTOT * 4);
  size_t o_cnt  = take(4 * NEXP);
  size_t o_ofs  = take(4 * (NEXP + 1));
  size_t o_cur  = take(4 * NEXP);
  size_t o_tmap = take(MAXT * 16);
  size_t total = off;

  hipMemsetAsync(d_out, 0, (size_t)T_TOK * HID * sizeof(float), stream);
  if (ws_size < total) {
    router_kernel<<<T_TOK / 4, 256, 0, stream>>>(x, gw, logits, nullptr, nullptr, nullptr,
                                                 nullptr, 0);
    return;
  }

  char* w = (char*)d_ws;
  u16* xb   = (u16*)(w + o_xb);
  u16* bi   = (u16*)(w + o_wt);
  u16* w2t  = bi;                                   // reused after gemm1 completes
  u16* hb   = (u16*)(w + o_hb);
  int*   rmap = (int*)(w + o_rmap);
  float* rw   = (float*)(w + o_rw);
  int*   tkid = (int*)(w + o_tid);
  float* tkw  = (float*)(w + o_tw);
  int*   cnt  = (int*)(w + o_cnt);
  int*   ofs  = (int*)(w + o_ofs);
  int*   cur  = (int*)(w + o_cur);
  int4*  tmap = (int4*)(w + o_tmap);

  hipMemsetAsync(cnt, 0, 4 * NEXP, stream);
  router_kernel<<<T_TOK / 4, 256, 0, stream>>>(x, gw, logits, tkid, tkw, cnt, xb, 1);
  scan_kernel<<<1, 64, 0, stream>>>(cnt, ofs, cur, tmap);
  scatter_kernel<<<RTOT / 256, 256, 0, stream>>>(tkid, tkw, ofs, cur, rmap, rw);
  transpose_cast_dual_kernel<<<dim3(FFN / 64, HID / 64, 2 * NEXP), 256, 0, stream>>>(w1, w3, bi);
  gemm1_kernel<<<NT1 * MAXT, 256, 0, stream>>>(xb, bi, rmap, tmap, hb);
  transpose_cast_w2_kernel<<<dim3(HID / 64, FFN / 64, NEXP), 256, 0, stream>>>(w2, w2t);
  gemm2_kernel<<<NT2 * MAXT * SPLITK2, 256, 0, stream>>>(hb, w2t, rmap, rw, tmap, out);
}

// Round 9
// 487.341 us; speedup vs baseline: 1.1035x; 1.1035x over previous
//
#include <hip/hip_runtime.h>
#include <hip/hip_bf16.h>
#include <cstdint>
#include <cstddef>

#define T_TOK 4096
#define HID   1024
#define FFN   3584
#define FFI   (2 * FFN)     // interleaved g/u columns: 7168
#define NEXP  8
#define RTOT  (T_TOK * 2)   // total (token, slot) rows = T * top_k
#define MAXT  72            // max 128-row M-tiles: floor(8192/128)+7=71, +1 slack
#define BM 128
#define BN 128
#define BK 64
#define NT1 (FFI / BN)      // 56 N-tiles for gemm1 (interleaved)
#define NT2 (HID / BN)      // 8 N-tiles for gemm2
#define SPLITK2 2           // gemm2 split-K (3584 -> 2 x 1792); partials stored, no atomics
#define KCH2 (FFN / SPLITK2)

typedef __attribute__((ext_vector_type(8))) short bvec8;   // 8 x bf16 (4 VGPR) MFMA operand
typedef __attribute__((ext_vector_type(4))) short bvec4;
typedef __attribute__((ext_vector_type(4))) float fvec4;   // MFMA accumulator
typedef unsigned short u16;

__device__ __forceinline__ u16 f2b(float f) {
  __bf16 b = (__bf16)f;                 // RNE convert
  return __builtin_bit_cast(u16, b);
}
__device__ __forceinline__ float b2f(u16 u) {
  unsigned v = (unsigned)u << 16;       // bf16 -> f32 exact
  return __builtin_bit_cast(float, v);
}

// async global->LDS, 16B per lane. LDS dest must be wave-uniform base (HW adds lane*16).
__device__ __forceinline__ void gload16(const u16* g, u16* l) {
  __builtin_amdgcn_global_load_lds((const __attribute__((address_space(1))) void*)g,
                                   (__attribute__((address_space(3))) void*)l, 16, 0, 0);
}

// bijective XCD swizzle (m204): contiguous chunk of work per XCD
__device__ __forceinline__ int xcd_swz(int bid, int nwg) {
  int q = nwg >> 3, r = nwg & 7;
  int xcd = bid & 7, sub = bid >> 3;
  return (xcd < r ? xcd * (q + 1) : r * (q + 1) + (xcd - r) * q) + sub;
}

// ---------------- router: logits (fp32), top-2, combine weights, counts, + x->bf16 ------
__global__ void router_kernel(const float* __restrict__ x, const float* __restrict__ gw,
                              float* __restrict__ logits, int* __restrict__ tk_id,
                              float* __restrict__ tk_w, int* __restrict__ counts,
                              u16* __restrict__ xb, int full) {
  const int lane = threadIdx.x & 63;
  const int wid  = threadIdx.x >> 6;
  const int t = blockIdx.x * 4 + wid;          // one token per wave
  const float4* xr = (const float4*)(x + (size_t)t * HID);
  float acc[NEXP] = {0.f, 0.f, 0.f, 0.f, 0.f, 0.f, 0.f, 0.f};
#pragma unroll
  for (int it = 0; it < 4; ++it) {
    int k4 = it * 64 + lane;                   // float4 index, covers H/4 = 256
    float4 xv = xr[k4];
    if (xb) {                                  // fused bf16 cast of x
      bvec4 o;
      o[0] = (short)f2b(xv.x); o[1] = (short)f2b(xv.y);
      o[2] = (short)f2b(xv.z); o[3] = (short)f2b(xv.w);
      *(bvec4*)(xb + (size_t)t * HID + k4 * 4) = o;
    }
    const float* gp = gw + (size_t)k4 * 4 * NEXP;
    float xs[4] = {xv.x, xv.y, xv.z, xv.w};
#pragma unroll
    for (int kk = 0; kk < 4; ++kk) {
      float4 ga = ((const float4*)(gp + kk * NEXP))[0];
      float4 gb = ((const float4*)(gp + kk * NEXP))[1];
      acc[0] += xs[kk] * ga.x; acc[1] += xs[kk] * ga.y;
      acc[2] += xs[kk] * ga.z; acc[3] += xs[kk] * ga.w;
      acc[4] += xs[kk] * gb.x; acc[5] += xs[kk] * gb.y;
      acc[6] += xs[kk] * gb.z; acc[7] += xs[kk] * gb.w;
    }
  }
#pragma unroll
  for (int off = 32; off > 0; off >>= 1) {
#pragma unroll
    for (int e = 0; e < NEXP; ++e) acc[e] += __shfl_xor(acc[e], off, 64);
  }
  if (lane < NEXP) logits[(size_t)t * NEXP + lane] = acc[lane];
  if (full && lane == 0) {
    int e0 = 0; float l0 = acc[0];
#pragma unroll
    for (int e = 1; e < NEXP; ++e) if (acc[e] > l0) { l0 = acc[e]; e0 = e; }
    int e1 = -1; float l1 = -3.4e38f;
#pragma unroll
    for (int e = 0; e < NEXP; ++e) if (e != e0 && acc[e] > l1) { l1 = acc[e]; e1 = e; }
    float w0 = 1.f / (1.f + expf(l1 - l0));
    float w1 = 1.f - w0;
    tk_id[t * 2 + 0] = e0; tk_id[t * 2 + 1] = e1;
    tk_w[t * 2 + 0] = w0;  tk_w[t * 2 + 1] = w1;
    atomicAdd(&counts[e0], 1); atomicAdd(&counts[e1], 1);
  }
}

// ---------------- scan: offsets, tile map (single thread; 8 experts, trivial) -----------
__global__ void scan_kernel(const int* __restrict__ counts, int* __restrict__ offsets,
                            int* __restrict__ cursors, int4* __restrict__ tilemap) {
  if (threadIdx.x != 0) return;
  int off = 0, nt = 0;
  for (int e = 0; e < NEXP; ++e) {
    offsets[e] = off; cursors[e] = 0;
    int c = counts[e];
    for (int tm = 0; tm * BM < c; ++tm)
      tilemap[nt++] = make_int4(e, off + tm * BM, min(BM, c - tm * BM), 0);
    off += c;
  }
  offsets[NEXP] = off;
  for (; nt < MAXT; ++nt) tilemap[nt] = make_int4(-1, 0, 0, 0);
}

// ---------------- scatter: row lists + inverse map token->rows --------------------------
__global__ void scatter_kernel(const int* __restrict__ tk_id, const float* __restrict__ tk_w,
                               const int* __restrict__ offsets, int* __restrict__ cursors,
                               int* __restrict__ rowmap, float* __restrict__ roww,
                               int* __restrict__ tokrow) {
  int i = blockIdx.x * 256 + threadIdx.x;      // 0 .. RTOT-1
  int t = i >> 1;
  int e = tk_id[i]; float w = tk_w[i];
  int p = atomicAdd(&cursors[e], 1);
  int r = offsets[e] + p;
  rowmap[r] = t; roww[r] = w;
  tokrow[i] = r;                               // slot i of token t lives at row r
}

// ---------------- transpose-cast w1/w3 -> interleaved Bi[E][FFI][HID] (LDS-staged) ------
__global__ void transpose_cast_dual_kernel(const float* __restrict__ w1,
                                           const float* __restrict__ w3,
                                           u16* __restrict__ bi) {
  __shared__ __attribute__((aligned(16))) u16 tile[64][72];
  const int z = blockIdx.z, e = z >> 1, half = z & 1;
  const float* src = (half ? w3 : w1) + (size_t)e * HID * FFN;   // [HID][FFN]
  u16* dst = bi + (size_t)e * FFI * HID;
  const int c0 = blockIdx.x * 64, r0 = blockIdx.y * 64;
  const int t = threadIdx.x;
  const int rr = t >> 4, cc = (t & 15) * 4;
#pragma unroll
  for (int it = 0; it < 4; ++it) {
    int r = it * 16 + rr;
    float4 v = *(const float4*)(src + (size_t)(r0 + r) * FFN + c0 + cc);
    tile[cc + 0][r] = f2b(v.x);
    tile[cc + 1][r] = f2b(v.y);
    tile[cc + 2][r] = f2b(v.z);
    tile[cc + 3][r] = f2b(v.w);
  }
  __syncthreads();
  const int cl = t >> 2;            // local col 0..63
  const int och = (t & 3) * 16;
  const int orow = (c0 << 1) + ((cl >> 4) << 5) + (cl & 15) + (half << 4);
  u16* dp = dst + (size_t)orow * HID + r0 + och;
  *(bvec8*)(dp + 0) = *(const bvec8*)&tile[cl][och + 0];
  *(bvec8*)(dp + 8) = *(const bvec8*)&tile[cl][och + 8];
}

// ---------------- transpose-cast w2 [E][FFN][HID] -> w2t [E][HID][FFN] (LDS-staged) -----
__global__ void transpose_cast_w2_kernel(const float* __restrict__ w2, u16* __restrict__ w2t) {
  __shared__ __attribute__((aligned(16))) u16 tile[64][72];
  const int e = blockIdx.z;
  const float* src = w2 + (size_t)e * FFN * HID;   // [FFN][HID]
  u16* dst = w2t + (size_t)e * HID * FFN;          // [HID][FFN]
  const int c0 = blockIdx.x * 64, r0 = blockIdx.y * 64;
  const int t = threadIdx.x;
  const int rr = t >> 4, cc = (t & 15) * 4;
#pragma unroll
  for (int it = 0; it < 4; ++it) {
    int r = it * 16 + rr;
    float4 v = *(const float4*)(src + (size_t)(r0 + r) * HID + c0 + cc);
    tile[cc + 0][r] = f2b(v.x);
    tile[cc + 1][r] = f2b(v.y);
    tile[cc + 2][r] = f2b(v.z);
    tile[cc + 3][r] = f2b(v.w);
  }
  __syncthreads();
  const int cl = t >> 2;
  const int och = (t & 3) * 16;
  u16* dp = dst + (size_t)(c0 + cl) * FFN + r0 + och;
  *(bvec8*)(dp + 0) = *(const bvec8*)&tile[cl][och + 0];
  *(bvec8*)(dp + 8) = *(const bvec8*)&tile[cl][och + 8];
}

// ---------------- GEMM1: 128x128, BK=64, proven R6 2-barrier structure ------------------
__launch_bounds__(256, 3)
__global__ void gemm1_kernel(const u16* __restrict__ xb, const u16* __restrict__ bi,
                             const int* __restrict__ rowmap,
                             const int4* __restrict__ tilemap, u16* __restrict__ hbuf) {
  const int wg = xcd_swz(blockIdx.x, NT1 * MAXT);
  const int mt = wg % MAXT;          // M fastest within an XCD chunk -> B-panel L2 reuse
  const int nt = wg / MAXT;
  int4 ti = tilemap[mt];
  if (ti.x < 0) return;
  const int e = ti.x, rowbase = ti.y, mvalid = ti.z;
  const int n0 = nt * BN;

  __shared__ __attribute__((aligned(128))) u16 As[BM * BK];   // 16KB
  __shared__ __attribute__((aligned(128))) u16 Bs[BN * BK];   // 16KB

  const int tid = threadIdx.x;
  const int lane = tid & 63;
  const int wv = tid >> 6;

  const int srow = tid >> 3;                         // 0..31
  const int csrc = ((tid & 7) ^ (srow & 7)) * 8;     // pre-swizzled source chunk (elems)
  const u16* wb = bi + (size_t)e * FFI * HID;
  const u16* gA[4]; const u16* gB[4];
  u16* lA[4]; u16* lB[4];
#pragma unroll
  for (int r = 0; r < 4; ++r) {
    int row = r * 32 + srow;
    int tok = rowmap[min(rowbase + row, RTOT - 1)];
    gA[r] = xb + (size_t)tok * HID + csrc;
    gB[r] = wb + (size_t)(n0 + row) * HID + csrc;
    lA[r] = &As[(r * 32 + wv * 8) * BK];             // wave-uniform dests
    lB[r] = &Bs[(r * 32 + wv * 8) * BK];
  }

  const int wm = (tid >> 7) & 1, wn = (tid >> 6) & 1;   // 2x2 waves, 64x64 each
  const int l15 = lane & 15;
  const int kg = lane >> 4;                          // 0..3
  const int swz = l15 & 7;
  const int aBase = (wm * 64 + l15) * BK;
  const int bBase = (wn * 64 + l15) * BK;
  const int ch0 = ((0 + kg) ^ swz) * 8;              // ks=0 phys chunk (elems)
  const int ch1 = ((4 + kg) ^ swz) * 8;              // ks=1

  fvec4 acc[4][4] = {};

  for (int kt = 0; kt < HID / BK; ++kt) {            // 16 iters
#pragma unroll
    for (int r = 0; r < 4; ++r) { gload16(gA[r], lA[r]); gA[r] += BK; }
#pragma unroll
    for (int r = 0; r < 4; ++r) { gload16(gB[r], lB[r]); gB[r] += BK; }
    __syncthreads();
    bvec8 a0[4], a1[4];
#pragma unroll
    for (int mi = 0; mi < 4; ++mi) {
      a0[mi] = *(const bvec8*)&As[aBase + mi * 16 * BK + ch0];
      a1[mi] = *(const bvec8*)&As[aBase + mi * 16 * BK + ch1];
    }
#pragma unroll
    for (int ni = 0; ni < 4; ++ni) {
      bvec8 b0 = *(const bvec8*)&Bs[bBase + ni * 16 * BK + ch0];
#pragma unroll
      for (int mi = 0; mi < 4; ++mi)
        acc[mi][ni] = __builtin_amdgcn_mfma_f32_16x16x32_bf16(a0[mi], b0, acc[mi][ni], 0, 0, 0);
      bvec8 b1 = *(const bvec8*)&Bs[bBase + ni * 16 * BK + ch1];
#pragma unroll
      for (int mi = 0; mi < 4; ++mi)
        acc[mi][ni] = __builtin_amdgcn_mfma_f32_16x16x32_bf16(a1[mi], b1, acc[mi][ni], 0, 0, 0);
    }
    __syncthreads();
  }
  // epilogue: pair ni (even=g, odd=u): h = silu(g) * u, bf16
  const int rg4 = (lane >> 4) * 4;
#pragma unroll
  for (int mi = 0; mi < 4; ++mi) {
#pragma unroll
    for (int j = 0; j < 4; ++j) {
      int ml = wm * 64 + mi * 16 + rg4 + j;
      if (ml < mvalid) {
        size_t rowoff = (size_t)(rowbase + ml) * FFN + ((n0 + wn * 64) >> 1);
#pragma unroll
        for (int np = 0; np < 2; ++np) {
          float g = acc[mi][2 * np][j], u = acc[mi][2 * np + 1][j];
          float hv = (g / (1.f + expf(-g))) * u;
          hbuf[rowoff + np * 16 + l15] = f2b(hv);
        }
      }
    }
  }
}

// ---------------- GEMM2: 128x128, BK=64, split-K x2, STORE epilogue (no atomics) --------
// Writes weighted bf16 partials: part[sk][row][HID]; each element written by exactly one
// block. Balance: 560 real blocks (~2.2/CU) vs 280. Combine kernel sums 4 partial reads.
__launch_bounds__(256, 3)
__global__ void gemm2_kernel(const u16* __restrict__ hbuf, const u16* __restrict__ w2t,
                             const float* __restrict__ roww,
                             const int4* __restrict__ tilemap, u16* __restrict__ part) {
  const int wg = xcd_swz(blockIdx.x, NT2 * MAXT * SPLITK2);
  const int mt = wg % MAXT;          // M fastest -> B-panel stays in XCD L2
  const int rest = wg / MAXT;
  const int nt = rest % NT2;
  const int sk = rest / NT2;         // 0..1: K chunk [sk*KCH2, (sk+1)*KCH2)
  int4 ti = tilemap[mt];
  if (ti.x < 0) return;
  const int e = ti.x, rowbase = ti.y, mvalid = ti.z;
  const int n0 = nt * BN;
  const int k0 = sk * KCH2;

  __shared__ __attribute__((aligned(128))) u16 As[BM * BK];   // 16KB
  __shared__ __attribute__((aligned(128))) u16 Bs[BN * BK];   // 16KB

  const int tid = threadIdx.x;
  const int lane = tid & 63;
  const int wv = tid >> 6;

  const int srow = tid >> 3;                         // 0..31
  const int csrc = ((tid & 7) ^ (srow & 7)) * 8;
  const u16* wb2 = w2t + (size_t)e * HID * FFN;
  const u16* gA[4]; const u16* gB[4];
  u16* lA[4]; u16* lB[4];
#pragma unroll
  for (int r = 0; r < 4; ++r) {
    int row = r * 32 + srow;
    gA[r] = hbuf + (size_t)min(rowbase + row, RTOT - 1) * FFN + k0 + csrc;
    gB[r] = wb2 + (size_t)(n0 + row) * FFN + k0 + csrc;
    lA[r] = &As[(r * 32 + wv * 8) * BK];
    lB[r] = &Bs[(r * 32 + wv * 8) * BK];
  }

  const int wm = (tid >> 7) & 1, wn = (tid >> 6) & 1;
  const int l15 = lane & 15;
  const int kg = lane >> 4;
  const int swz = l15 & 7;
  const int aBase = (wm * 64 + l15) * BK;
  const int bBase = (wn * 64 + l15) * BK;
  const int ch0 = ((0 + kg) ^ swz) * 8;
  const int ch1 = ((4 + kg) ^ swz) * 8;

  fvec4 acc[4][4] = {};

  for (int kt = 0; kt < KCH2 / BK; ++kt) {           // 28 iters
#pragma unroll
    for (int r = 0; r < 4; ++r) { gload16(gA[r], lA[r]); gA[r] += BK; }
#pragma unroll
    for (int r = 0; r < 4; ++r) { gload16(gB[r], lB[r]); gB[r] += BK; }
    __syncthreads();
    bvec8 a0[4], a1[4];
#pragma unroll
    for (int mi = 0; mi < 4; ++mi) {
      a0[mi] = *(const bvec8*)&As[aBase + mi * 16 * BK + ch0];
      a1[mi] = *(const bvec8*)&As[aBase + mi * 16 * BK + ch1];
    }
#pragma unroll
    for (int ni = 0; ni < 4; ++ni) {
      bvec8 b0 = *(const bvec8*)&Bs[bBase + ni * 16 * BK + ch0];
#pragma unroll
      for (int mi = 0; mi < 4; ++mi)
        acc[mi][ni] = __builtin_amdgcn_mfma_f32_16x16x32_bf16(a0[mi], b0, acc[mi][ni], 0, 0, 0);
      bvec8 b1 = *(const bvec8*)&Bs[bBase + ni * 16 * BK + ch1];
#pragma unroll
      for (int mi = 0; mi < 4; ++mi)
        acc[mi][ni] = __builtin_amdgcn_mfma_f32_16x16x32_bf16(a1[mi], b1, acc[mi][ni], 0, 0, 0);
    }
    __syncthreads();
  }
  // epilogue: weighted bf16 partial store (plain stores, no atomics)
  u16* pp = part + (size_t)sk * RTOT * HID;
  const int rg4 = (lane >> 4) * 4;
#pragma unroll
  for (int mi = 0; mi < 4; ++mi) {
#pragma unroll
    for (int j = 0; j < 4; ++j) {
      int ml = wm * 64 + mi * 16 + rg4 + j;
      if (ml < mvalid) {
        int r = rowbase + ml;
        float wgt = roww[r];
        u16* op = pp + (size_t)r * HID + n0 + wn * 64;
#pragma unroll
        for (int ni = 0; ni < 4; ++ni)
          op[ni * 16 + l15] = f2b(acc[mi][ni][j] * wgt);
      }
    }
  }
}

// ---------------- combine: out[t] = sum over {2 slots} x {2 K-halves} of partials -------
__global__ void combine_kernel(const u16* __restrict__ part, const int* __restrict__ tokrow,
                               float* __restrict__ out) {
  int idx = blockIdx.x * 256 + threadIdx.x;    // 8-col chunk id
  int t = idx >> 7;                            // 128 chunks per token (1024/8)
  int c = (idx & 127) * 8;
  int r0 = tokrow[2 * t], r1 = tokrow[2 * t + 1];
  const size_t sk1 = (size_t)RTOT * HID;
  bvec8 a = *(const bvec8*)(part + (size_t)r0 * HID + c);
  bvec8 b = *(const bvec8*)(part + sk1 + (size_t)r0 * HID + c);
  bvec8 d = *(const bvec8*)(part + (size_t)r1 * HID + c);
  bvec8 f = *(const bvec8*)(part + sk1 + (size_t)r1 * HID + c);
  float* dst = out + (size_t)t * HID + c;
#pragma unroll
  for (int k = 0; k < 8; ++k)
    dst[k] = (b2f((u16)a[k]) + b2f((u16)b[k])) + (b2f((u16)d[k]) + b2f((u16)f[k]));
}

// ---------------- launcher --------------------------------------------------------------
extern "C" void kernel_launch(void* const* d_in, const int* in_sizes, int n_in,
                              void* d_out, int out_size, void* d_ws, size_t ws_size,
                              hipStream_t stream) {
  (void)in_sizes; (void)n_in; (void)out_size;
  const float* x  = (const float*)d_in[0];
  const float* gw = (const float*)d_in[1];
  const float* w1 = (const float*)d_in[2];
  const float* w2 = (const float*)d_in[3];   // NOTE: dict order is w1, w2, w3
  const float* w3 = (const float*)d_in[4];
  float* out = (float*)d_out;
  float* logits = out + (size_t)T_TOK * HID;

  size_t off = 0;
  auto take = [&](size_t b) { size_t o = off; off += (b + 255) & ~(size_t)255; return o; };
  size_t o_xb   = take((size_t)T_TOK * HID * 2);           // x bf16
  size_t o_wt   = take((size_t)NEXP * FFI * HID * 2);      // Bi; later: w2t (front) + part (back)
  size_t o_hb   = take((size_t)RTOT * FFN * 2);            // h bf16
  size_t o_rmap = take((size_t)RTOT * 4);
  size_t o_rw   = take((size_t)RTOT * 4);
  size_t o_tid  = take((size_t)RTOT * 4);
  size_t o_tw   = take((size_t)RTOT * 4);
  size_t o_trow = take((size_t)RTOT * 4);
  size_t o_cnt  = take(4 * NEXP);
  size_t o_ofs  = take(4 * (NEXP + 1));
  size_t o_cur  = take(4 * NEXP);
  size_t o_tmap = take(MAXT * 16);
  size_t total = off;

  if (ws_size < total) {
    hipMemsetAsync(d_out, 0, (size_t)T_TOK * HID * sizeof(float), stream);
    router_kernel<<<T_TOK / 4, 256, 0, stream>>>(x, gw, logits, nullptr, nullptr, nullptr,
                                                 nullptr, 0);
    return;
  }

  char* w = (char*)d_ws;
  u16* xb   = (u16*)(w + o_xb);
  u16* bi   = (u16*)(w + o_wt);
  u16* w2t  = bi;                                   // front 56MB, reused after gemm1
  u16* part = bi + (size_t)NEXP * HID * FFN;        // back 58.7MB free region: 2x16.7MB
  u16* hb   = (u16*)(w + o_hb);
  int*   rmap = (int*)(w + o_rmap);
  float* rw   = (float*)(w + o_rw);
  int*   tkid = (int*)(w + o_tid);
  float* tkw  = (float*)(w + o_tw);
  int*   trow = (int*)(w + o_trow);
  int*   cnt  = (int*)(w + o_cnt);
  int*   ofs  = (int*)(w + o_ofs);
  int*   cur  = (int*)(w + o_cur);
  int4*  tmap = (int4*)(w + o_tmap);

  hipMemsetAsync(cnt, 0, 4 * NEXP, stream);
  router_kernel<<<T_TOK / 4, 256, 0, stream>>>(x, gw, logits, tkid, tkw, cnt, xb, 1);
  scan_kernel<<<1, 64, 0, stream>>>(cnt, ofs, cur, tmap);
  scatter_kernel<<<RTOT / 256, 256, 0, stream>>>(tkid, tkw, ofs, cur, rmap, rw, trow);
  transpose_cast_dual_kernel<<<dim3(FFN / 64, HID / 64, 2 * NEXP), 256, 0, stream>>>(w1, w3, bi);
  gemm1_kernel<<<NT1 * MAXT, 256, 0, stream>>>(xb, bi, rmap, tmap, hb);
  transpose_cast_w2_kernel<<<dim3(HID / 64, FFN / 64, NEXP), 256, 0, stream>>>(w2, w2t);
  gemm2_kernel<<<NT2 * MAXT * SPLITK2, 256, 0, stream>>>(hb, w2t, rw, tmap, part);
  combine_kernel<<<T_TOK * HID / 8 / 256, 256, 0, stream>>>(part, trow, out);
}

// Round 10
// 487.313 us; speedup vs baseline: 1.1036x; 1.0001x over previous
//
#include <hip/hip_runtime.h>
#include <hip/hip_bf16.h>
#include <cstdint>
#include <cstddef>

#define T_TOK 4096
#define HID   1024
#define FFN   3584
#define FFI   (2 * FFN)     // interleaved g/u columns: 7168
#define NEXP  8
#define RTOT  (T_TOK * 2)   // total (token, slot) rows = T * top_k
#define MAXT  72            // max 128-row M-tiles: floor(8192/128)+7=71, +1 slack
#define BM 128
#define BN 128
#define BK 64
#define NT1 (FFI / BN)      // 56 N-tiles for gemm1 (interleaved)
#define NT2 (HID / BN)      // 8 N-tiles for gemm2
#define SPLITK2 2           // gemm2 split-K (3584 -> 2 x 1792); partials stored, no atomics
#define KCH2 (FFN / SPLITK2)

typedef __attribute__((ext_vector_type(8))) short bvec8;   // 8 x bf16 (4 VGPR) MFMA operand
typedef __attribute__((ext_vector_type(4))) short bvec4;
typedef __attribute__((ext_vector_type(4))) float fvec4;   // MFMA accumulator
typedef unsigned short u16;

__device__ __forceinline__ u16 f2b(float f) {
  __bf16 b = (__bf16)f;                 // RNE convert
  return __builtin_bit_cast(u16, b);
}
__device__ __forceinline__ float b2f(u16 u) {
  unsigned v = (unsigned)u << 16;       // bf16 -> f32 exact
  return __builtin_bit_cast(float, v);
}

// async global->LDS, 16B per lane. LDS dest must be wave-uniform base (HW adds lane*16).
__device__ __forceinline__ void gload16(const u16* g, u16* l) {
  __builtin_amdgcn_global_load_lds((const __attribute__((address_space(1))) void*)g,
                                   (__attribute__((address_space(3))) void*)l, 16, 0, 0);
}

// bijective XCD swizzle (m204): contiguous chunk of work per XCD
__device__ __forceinline__ int xcd_swz(int bid, int nwg) {
  int q = nwg >> 3, r = nwg & 7;
  int xcd = bid & 7, sub = bid >> 3;
  return (xcd < r ? xcd * (q + 1) : r * (q + 1) + (xcd - r) * q) + sub;
}

// ---------------- router: logits (fp32), top-2, combine weights, counts, + x->bf16 ------
__global__ void router_kernel(const float* __restrict__ x, const float* __restrict__ gw,
                              float* __restrict__ logits, int* __restrict__ tk_id,
                              float* __restrict__ tk_w, int* __restrict__ counts,
                              u16* __restrict__ xb, int full) {
  const int lane = threadIdx.x & 63;
  const int wid  = threadIdx.x >> 6;
  const int t = blockIdx.x * 4 + wid;          // one token per wave
  const float4* xr = (const float4*)(x + (size_t)t * HID);
  float acc[NEXP] = {0.f, 0.f, 0.f, 0.f, 0.f, 0.f, 0.f, 0.f};
#pragma unroll
  for (int it = 0; it < 4; ++it) {
    int k4 = it * 64 + lane;                   // float4 index, covers H/4 = 256
    float4 xv = xr[k4];
    if (xb) {                                  // fused bf16 cast of x
      bvec4 o;
      o[0] = (short)f2b(xv.x); o[1] = (short)f2b(xv.y);
      o[2] = (short)f2b(xv.z); o[3] = (short)f2b(xv.w);
      *(bvec4*)(xb + (size_t)t * HID + k4 * 4) = o;
    }
    const float* gp = gw + (size_t)k4 * 4 * NEXP;
    float xs[4] = {xv.x, xv.y, xv.z, xv.w};
#pragma unroll
    for (int kk = 0; kk < 4; ++kk) {
      float4 ga = ((const float4*)(gp + kk * NEXP))[0];
      float4 gb = ((const float4*)(gp + kk * NEXP))[1];
      acc[0] += xs[kk] * ga.x; acc[1] += xs[kk] * ga.y;
      acc[2] += xs[kk] * ga.z; acc[3] += xs[kk] * ga.w;
      acc[4] += xs[kk] * gb.x; acc[5] += xs[kk] * gb.y;
      acc[6] += xs[kk] * gb.z; acc[7] += xs[kk] * gb.w;
    }
  }
#pragma unroll
  for (int off = 32; off > 0; off >>= 1) {
#pragma unroll
    for (int e = 0; e < NEXP; ++e) acc[e] += __shfl_xor(acc[e], off, 64);
  }
  if (lane < NEXP) logits[(size_t)t * NEXP + lane] = acc[lane];
  if (full && lane == 0) {
    int e0 = 0; float l0 = acc[0];
#pragma unroll
    for (int e = 1; e < NEXP; ++e) if (acc[e] > l0) { l0 = acc[e]; e0 = e; }
    int e1 = -1; float l1 = -3.4e38f;
#pragma unroll
    for (int e = 0; e < NEXP; ++e) if (e != e0 && acc[e] > l1) { l1 = acc[e]; e1 = e; }
    float w0 = 1.f / (1.f + expf(l1 - l0));
    float w1 = 1.f - w0;
    tk_id[t * 2 + 0] = e0; tk_id[t * 2 + 1] = e1;
    tk_w[t * 2 + 0] = w0;  tk_w[t * 2 + 1] = w1;
    atomicAdd(&counts[e0], 1); atomicAdd(&counts[e1], 1);
  }
}

// ---------------- scan: offsets, tile map (single thread; 8 experts, trivial) -----------
__global__ void scan_kernel(const int* __restrict__ counts, int* __restrict__ offsets,
                            int* __restrict__ cursors, int4* __restrict__ tilemap) {
  if (threadIdx.x != 0) return;
  int off = 0, nt = 0;
  for (int e = 0; e < NEXP; ++e) {
    offsets[e] = off; cursors[e] = 0;
    int c = counts[e];
    for (int tm = 0; tm * BM < c; ++tm)
      tilemap[nt++] = make_int4(e, off + tm * BM, min(BM, c - tm * BM), 0);
    off += c;
  }
  offsets[NEXP] = off;
  for (; nt < MAXT; ++nt) tilemap[nt] = make_int4(-1, 0, 0, 0);
}

// ---------------- scatter: row lists + inverse map token->rows --------------------------
__global__ void scatter_kernel(const int* __restrict__ tk_id, const float* __restrict__ tk_w,
                               const int* __restrict__ offsets, int* __restrict__ cursors,
                               int* __restrict__ rowmap, float* __restrict__ roww,
                               int* __restrict__ tokrow) {
  int i = blockIdx.x * 256 + threadIdx.x;      // 0 .. RTOT-1
  int t = i >> 1;
  int e = tk_id[i]; float w = tk_w[i];
  int p = atomicAdd(&cursors[e], 1);
  int r = offsets[e] + p;
  rowmap[r] = t; roww[r] = w;
  tokrow[i] = r;                               // slot i of token t lives at row r
}

// ---------------- transpose-cast (conflict-light): fp32 [R][C] 64x64 tile -> bf16 ------
// Phase 1: thread (m=t&15, g=t>>4) reads 4x4 block rows 4g..+3 / cols 4m..+3 (coalesced),
// converts + transposes in-reg, writes 4x bvec4 into chunk-XOR-swizzled tile
// (phys_chunk = g ^ ((m&3)<<2); bijective, touches only chunk bits 2-3).
// Phase 2: thread (cl=t>>2, q=t&3) reads 2x bvec8 at swizzled base, writes coalesced.
__global__ void transpose_cast_dual_kernel(const float* __restrict__ w1,
                                           const float* __restrict__ w3,
                                           u16* __restrict__ bi) {
  __shared__ __attribute__((aligned(16))) u16 tile[64 * 72];
  const int z = blockIdx.z, e = z >> 1, half = z & 1;
  const float* src = (half ? w3 : w1) + (size_t)e * HID * FFN;   // [HID][FFN]
  u16* dst = bi + (size_t)e * FFI * HID;
  const int c0 = blockIdx.x * 64, r0 = blockIdx.y * 64;
  const int t = threadIdx.x;
  const int m = t & 15;             // col-group (cols 4m..4m+3)
  const int g = t >> 4;             // row-group (rows 4g..4g+3)
  u16 v[4][4];                      // v[i][j] = elem(row 4g+i, col 4m+j)
#pragma unroll
  for (int i = 0; i < 4; ++i) {
    float4 q = *(const float4*)(src + (size_t)(r0 + 4 * g + i) * FFN + c0 + 4 * m);
    v[i][0] = f2b(q.x); v[i][1] = f2b(q.y); v[i][2] = f2b(q.z); v[i][3] = f2b(q.w);
  }
  const int phys = (g ^ ((m & 3) << 2)) * 4;   // swizzled chunk offset (u16)
#pragma unroll
  for (int j = 0; j < 4; ++j) {
    int c = 4 * m + j;
    bvec4 o; o[0] = (short)v[0][j]; o[1] = (short)v[1][j];
    o[2] = (short)v[2][j]; o[3] = (short)v[3][j];
    *(bvec4*)&tile[c * 72 + phys] = o;
  }
  __syncthreads();
  const int cl = t >> 2;            // output row (source col) 0..63
  const int q  = t & 3;             // 16-elem r-group
  const int base = ((q ^ ((cl >> 2) & 3)) << 4);    // swizzled 16-u16 group offset
  bvec8 ra = *(const bvec8*)&tile[cl * 72 + base];
  bvec8 rb = *(const bvec8*)&tile[cl * 72 + base + 8];
  const int orow = (c0 << 1) + ((cl >> 4) << 5) + (cl & 15) + (half << 4);
  u16* dp = dst + (size_t)orow * HID + r0 + 16 * q;
  *(bvec8*)(dp + 0) = ra;
  *(bvec8*)(dp + 8) = rb;
}

// ---------------- transpose-cast w2 [E][FFN][HID] -> w2t [E][HID][FFN] (same scheme) ----
__global__ void transpose_cast_w2_kernel(const float* __restrict__ w2, u16* __restrict__ w2t) {
  __shared__ __attribute__((aligned(16))) u16 tile[64 * 72];
  const int e = blockIdx.z;
  const float* src = w2 + (size_t)e * FFN * HID;   // [FFN][HID]
  u16* dst = w2t + (size_t)e * HID * FFN;          // [HID][FFN]
  const int c0 = blockIdx.x * 64, r0 = blockIdx.y * 64;
  const int t = threadIdx.x;
  const int m = t & 15;
  const int g = t >> 4;
  u16 v[4][4];
#pragma unroll
  for (int i = 0; i < 4; ++i) {
    float4 q = *(const float4*)(src + (size_t)(r0 + 4 * g + i) * HID + c0 + 4 * m);
    v[i][0] = f2b(q.x); v[i][1] = f2b(q.y); v[i][2] = f2b(q.z); v[i][3] = f2b(q.w);
  }
  const int phys = (g ^ ((m & 3) << 2)) * 4;
#pragma unroll
  for (int j = 0; j < 4; ++j) {
    int c = 4 * m + j;
    bvec4 o; o[0] = (short)v[0][j]; o[1] = (short)v[1][j];
    o[2] = (short)v[2][j]; o[3] = (short)v[3][j];
    *(bvec4*)&tile[c * 72 + phys] = o;
  }
  __syncthreads();
  const int cl = t >> 2;
  const int q  = t & 3;
  const int base = ((q ^ ((cl >> 2) & 3)) << 4);
  bvec8 ra = *(const bvec8*)&tile[cl * 72 + base];
  bvec8 rb = *(const bvec8*)&tile[cl * 72 + base + 8];
  u16* dp = dst + (size_t)(c0 + cl) * FFN + r0 + 16 * q;
  *(bvec8*)(dp + 0) = ra;
  *(bvec8*)(dp + 8) = rb;
}

// ---------------- GEMM1: 128x128, BK=64, proven R6 2-barrier structure ------------------
__launch_bounds__(256, 3)
__global__ void gemm1_kernel(const u16* __restrict__ xb, const u16* __restrict__ bi,
                             const int* __restrict__ rowmap,
                             const int4* __restrict__ tilemap, u16* __restrict__ hbuf) {
  const int wg = xcd_swz(blockIdx.x, NT1 * MAXT);
  const int mt = wg % MAXT;          // M fastest within an XCD chunk -> B-panel L2 reuse
  const int nt = wg / MAXT;
  int4 ti = tilemap[mt];
  if (ti.x < 0) return;
  const int e = ti.x, rowbase = ti.y, mvalid = ti.z;
  const int n0 = nt * BN;

  __shared__ __attribute__((aligned(128))) u16 As[BM * BK];   // 16KB
  __shared__ __attribute__((aligned(128))) u16 Bs[BN * BK];   // 16KB

  const int tid = threadIdx.x;
  const int lane = tid & 63;
  const int wv = tid >> 6;

  const int srow = tid >> 3;                         // 0..31
  const int csrc = ((tid & 7) ^ (srow & 7)) * 8;     // pre-swizzled source chunk (elems)
  const u16* wb = bi + (size_t)e * FFI * HID;
  const u16* gA[4]; const u16* gB[4];
  u16* lA[4]; u16* lB[4];
#pragma unroll
  for (int r = 0; r < 4; ++r) {
    int row = r * 32 + srow;
    int tok = rowmap[min(rowbase + row, RTOT - 1)];
    gA[r] = xb + (size_t)tok * HID + csrc;
    gB[r] = wb + (size_t)(n0 + row) * HID + csrc;
    lA[r] = &As[(r * 32 + wv * 8) * BK];             // wave-uniform dests
    lB[r] = &Bs[(r * 32 + wv * 8) * BK];
  }

  const int wm = (tid >> 7) & 1, wn = (tid >> 6) & 1;   // 2x2 waves, 64x64 each
  const int l15 = lane & 15;
  const int kg = lane >> 4;                          // 0..3
  const int swz = l15 & 7;
  const int aBase = (wm * 64 + l15) * BK;
  const int bBase = (wn * 64 + l15) * BK;
  const int ch0 = ((0 + kg) ^ swz) * 8;              // ks=0 phys chunk (elems)
  const int ch1 = ((4 + kg) ^ swz) * 8;              // ks=1

  fvec4 acc[4][4] = {};

  for (int kt = 0; kt < HID / BK; ++kt) {            // 16 iters
#pragma unroll
    for (int r = 0; r < 4; ++r) { gload16(gA[r], lA[r]); gA[r] += BK; }
#pragma unroll
    for (int r = 0; r < 4; ++r) { gload16(gB[r], lB[r]); gB[r] += BK; }
    __syncthreads();
    bvec8 a0[4], a1[4];
#pragma unroll
    for (int mi = 0; mi < 4; ++mi) {
      a0[mi] = *(const bvec8*)&As[aBase + mi * 16 * BK + ch0];
      a1[mi] = *(const bvec8*)&As[aBase + mi * 16 * BK + ch1];
    }
#pragma unroll
    for (int ni = 0; ni < 4; ++ni) {
      bvec8 b0 = *(const bvec8*)&Bs[bBase + ni * 16 * BK + ch0];
#pragma unroll
      for (int mi = 0; mi < 4; ++mi)
        acc[mi][ni] = __builtin_amdgcn_mfma_f32_16x16x32_bf16(a0[mi], b0, acc[mi][ni], 0, 0, 0);
      bvec8 b1 = *(const bvec8*)&Bs[bBase + ni * 16 * BK + ch1];
#pragma unroll
      for (int mi = 0; mi < 4; ++mi)
        acc[mi][ni] = __builtin_amdgcn_mfma_f32_16x16x32_bf16(a1[mi], b1, acc[mi][ni], 0, 0, 0);
    }
    __syncthreads();
  }
  // epilogue: pair ni (even=g, odd=u): h = silu(g) * u, bf16
  const int rg4 = (lane >> 4) * 4;
#pragma unroll
  for (int mi = 0; mi < 4; ++mi) {
#pragma unroll
    for (int j = 0; j < 4; ++j) {
      int ml = wm * 64 + mi * 16 + rg4 + j;
      if (ml < mvalid) {
        size_t rowoff = (size_t)(rowbase + ml) * FFN + ((n0 + wn * 64) >> 1);
#pragma unroll
        for (int np = 0; np < 2; ++np) {
          float g = acc[mi][2 * np][j], u = acc[mi][2 * np + 1][j];
          float hv = (g / (1.f + expf(-g))) * u;
          hbuf[rowoff + np * 16 + l15] = f2b(hv);
        }
      }
    }
  }
}

// ---------------- GEMM2: 128x128, BK=64, split-K x2, STORE epilogue (no atomics) --------
__launch_bounds__(256, 3)
__global__ void gemm2_kernel(const u16* __restrict__ hbuf, const u16* __restrict__ w2t,
                             const float* __restrict__ roww,
                             const int4* __restrict__ tilemap, u16* __restrict__ part) {
  const int wg = xcd_swz(blockIdx.x, NT2 * MAXT * SPLITK2);
  const int mt = wg % MAXT;          // M fastest -> B-panel stays in XCD L2
  const int rest = wg / MAXT;
  const int nt = rest % NT2;
  const int sk = rest / NT2;         // 0..1: K chunk [sk*KCH2, (sk+1)*KCH2)
  int4 ti = tilemap[mt];
  if (ti.x < 0) return;
  const int e = ti.x, rowbase = ti.y, mvalid = ti.z;
  const int n0 = nt * BN;
  const int k0 = sk * KCH2;

  __shared__ __attribute__((aligned(128))) u16 As[BM * BK];   // 16KB
  __shared__ __attribute__((aligned(128))) u16 Bs[BN * BK];   // 16KB

  const int tid = threadIdx.x;
  const int lane = tid & 63;
  const int wv = tid >> 6;

  const int srow = tid >> 3;                         // 0..31
  const int csrc = ((tid & 7) ^ (srow & 7)) * 8;
  const u16* wb2 = w2t + (size_t)e * HID * FFN;
  const u16* gA[4]; const u16* gB[4];
  u16* lA[4]; u16* lB[4];
#pragma unroll
  for (int r = 0; r < 4; ++r) {
    int row = r * 32 + srow;
    gA[r] = hbuf + (size_t)min(rowbase + row, RTOT - 1) * FFN + k0 + csrc;
    gB[r] = wb2 + (size_t)(n0 + row) * FFN + k0 + csrc;
    lA[r] = &As[(r * 32 + wv * 8) * BK];
    lB[r] = &Bs[(r * 32 + wv * 8) * BK];
  }

  const int wm = (tid >> 7) & 1, wn = (tid >> 6) & 1;
  const int l15 = lane & 15;
  const int kg = lane >> 4;
  const int swz = l15 & 7;
  const int aBase = (wm * 64 + l15) * BK;
  const int bBase = (wn * 64 + l15) * BK;
  const int ch0 = ((0 + kg) ^ swz) * 8;
  const int ch1 = ((4 + kg) ^ swz) * 8;

  fvec4 acc[4][4] = {};

  for (int kt = 0; kt < KCH2 / BK; ++kt) {           // 28 iters
#pragma unroll
    for (int r = 0; r < 4; ++r) { gload16(gA[r], lA[r]); gA[r] += BK; }
#pragma unroll
    for (int r = 0; r < 4; ++r) { gload16(gB[r], lB[r]); gB[r] += BK; }
    __syncthreads();
    bvec8 a0[4], a1[4];
#pragma unroll
    for (int mi = 0; mi < 4; ++mi) {
      a0[mi] = *(const bvec8*)&As[aBase + mi * 16 * BK + ch0];
      a1[mi] = *(const bvec8*)&As[aBase + mi * 16 * BK + ch1];
    }
#pragma unroll
    for (int ni = 0; ni < 4; ++ni) {
      bvec8 b0 = *(const bvec8*)&Bs[bBase + ni * 16 * BK + ch0];
#pragma unroll
      for (int mi = 0; mi < 4; ++mi)
        acc[mi][ni] = __builtin_amdgcn_mfma_f32_16x16x32_bf16(a0[mi], b0, acc[mi][ni], 0, 0, 0);
      bvec8 b1 = *(const bvec8*)&Bs[bBase + ni * 16 * BK + ch1];
#pragma unroll
      for (int mi = 0; mi < 4; ++mi)
        acc[mi][ni] = __builtin_amdgcn_mfma_f32_16x16x32_bf16(a1[mi], b1, acc[mi][ni], 0, 0, 0);
    }
    __syncthreads();
  }
  // epilogue: weighted bf16 partial store (plain stores, no atomics)
  u16* pp = part + (size_t)sk * RTOT * HID;
  const int rg4 = (lane >> 4) * 4;
#pragma unroll
  for (int mi = 0; mi < 4; ++mi) {
#pragma unroll
    for (int j = 0; j < 4; ++j) {
      int ml = wm * 64 + mi * 16 + rg4 + j;
      if (ml < mvalid) {
        int r = rowbase + ml;
        float wgt = roww[r];
        u16* op = pp + (size_t)r * HID + n0 + wn * 64;
#pragma unroll
        for (int ni = 0; ni < 4; ++ni)
          op[ni * 16 + l15] = f2b(acc[mi][ni][j] * wgt);
      }
    }
  }
}

// ---------------- combine: out[t] = sum over {2 slots} x {2 K-halves} of partials -------
__global__ void combine_kernel(const u16* __restrict__ part, const int* __restrict__ tokrow,
                               float* __restrict__ out) {
  int idx = blockIdx.x * 256 + threadIdx.x;    // 8-col chunk id
  int t = idx >> 7;                            // 128 chunks per token (1024/8)
  int c = (idx & 127) * 8;
  int r0 = tokrow[2 * t], r1 = tokrow[2 * t + 1];
  const size_t sk1 = (size_t)RTOT * HID;
  bvec8 a = *(const bvec8*)(part + (size_t)r0 * HID + c);
  bvec8 b = *(const bvec8*)(part + sk1 + (size_t)r0 * HID + c);
  bvec8 d = *(const bvec8*)(part + (size_t)r1 * HID + c);
  bvec8 f = *(const bvec8*)(part + sk1 + (size_t)r1 * HID + c);
  float* dst = out + (size_t)t * HID + c;
#pragma unroll
  for (int k = 0; k < 8; ++k)
    dst[k] = (b2f((u16)a[k]) + b2f((u16)b[k])) + (b2f((u16)d[k]) + b2f((u16)f[k]));
}

// ---------------- launcher --------------------------------------------------------------
extern "C" void kernel_launch(void* const* d_in, const int* in_sizes, int n_in,
                              void* d_out, int out_size, void* d_ws, size_t ws_size,
                              hipStream_t stream) {
  (void)in_sizes; (void)n_in; (void)out_size;
  const float* x  = (const float*)d_in[0];
  const float* gw = (const float*)d_in[1];
  const float* w1 = (const float*)d_in[2];
  const float* w2 = (const float*)d_in[3];   // NOTE: dict order is w1, w2, w3
  const float* w3 = (const float*)d_in[4];
  float* out = (float*)d_out;
  float* logits = out + (size_t)T_TOK * HID;

  size_t off = 0;
  auto take = [&](size_t b) { size_t o = off; off += (b + 255) & ~(size_t)255; return o; };
  size_t o_xb   = take((size_t)T_TOK * HID * 2);           // x bf16
  size_t o_wt   = take((size_t)NEXP * FFI * HID * 2);      // Bi; later: w2t (front) + part (back)
  size_t o_hb   = take((size_t)RTOT * FFN * 2);            // h bf16
  size_t o_rmap = take((size_t)RTOT * 4);
  size_t o_rw   = take((size_t)RTOT * 4);
  size_t o_tid  = take((size_t)RTOT * 4);
  size_t o_tw   = take((size_t)RTOT * 4);
  size_t o_trow = take((size_t)RTOT * 4);
  size_t o_cnt  = take(4 * NEXP);
  size_t o_ofs  = take(4 * (NEXP + 1));
  size_t o_cur  = take(4 * NEXP);
  size_t o_tmap = take(MAXT * 16);
  size_t total = off;

  if (ws_size < total) {
    hipMemsetAsync(d_out, 0, (size_t)T_TOK * HID * sizeof(float), stream);
    router_kernel<<<T_TOK / 4, 256, 0, stream>>>(x, gw, logits, nullptr, nullptr, nullptr,
                                                 nullptr, 0);
    return;
  }

  char* w = (char*)d_ws;
  u16* xb   = (u16*)(w + o_xb);
  u16* bi   = (u16*)(w + o_wt);
  u16* w2t  = bi;                                   // front 56MB, reused after gemm1
  u16* part = bi + (size_t)NEXP * HID * FFN;        // back 58.7MB free region: 2x16.7MB
  u16* hb   = (u16*)(w + o_hb);
  int*   rmap = (int*)(w + o_rmap);
  float* rw   = (float*)(w + o_rw);
  int*   tkid = (int*)(w + o_tid);
  float* tkw  = (float*)(w + o_tw);
  int*   trow = (int*)(w + o_trow);
  int*   cnt  = (int*)(w + o_cnt);
  int*   ofs  = (int*)(w + o_ofs);
  int*   cur  = (int*)(w + o_cur);
  int4*  tmap = (int4*)(w + o_tmap);

  hipMemsetAsync(cnt, 0, 4 * NEXP, stream);
  router_kernel<<<T_TOK / 4, 256, 0, stream>>>(x, gw, logits, tkid, tkw, cnt, xb, 1);
  scan_kernel<<<1, 64, 0, stream>>>(cnt, ofs, cur, tmap);
  scatter_kernel<<<RTOT / 256, 256, 0, stream>>>(tkid, tkw, ofs, cur, rmap, rw, trow);
  transpose_cast_dual_kernel<<<dim3(FFN / 64, HID / 64, 2 * NEXP), 256, 0, stream>>>(w1, w3, bi);
  gemm1_kernel<<<NT1 * MAXT, 256, 0, stream>>>(xb, bi, rmap, tmap, hb);
  transpose_cast_w2_kernel<<<dim3(HID / 64, FFN / 64, NEXP), 256, 0, stream>>>(w2, w2t);
  gemm2_kernel<<<NT2 * MAXT * SPLITK2, 256, 0, stream>>>(hb, w2t, rw, tmap, part);
  combine_kernel<<<T_TOK * HID / 8 / 256, 256, 0, stream>>>(part, trow, out);
}